// Round 4
// baseline (382.382 us; speedup 1.0000x reference)
//
#include <hip/hip_runtime.h>
#include <stdint.h>
#include <math.h>

// OTLoss: ft(4096x1024), fs(4096x1024) fp32 -> (loss, P[4096x4096], M[4096x4096])
//
// Pipeline:
//  1) norm_rows2 (fused): row-normalize ft,fs -> bf16 A,B; block 0 zeroes
//     scal + barrier flags (replay-safe)
//  2) M_raw = A @ B^T via mfma_f32_16x16x32_bf16, 128x128 tiles, global_load_lds
//     epilogue: per-block partial sum/sumsq + per-(bn,waveN) row maxes, plain
//     stores only (contended atomics removed in r3: was ~8192 serialized RMWs)
//  3) ONE persistent kernel (PLAIN launch, 256 blocks x 512 thr, 1/CU):
//     grid=256=#CUs and VGPR<=256 guarantee co-residency -> grid barrier safe
//     without cooperative launch (coop launch cost ~90us under graph replay, r2/r3).
//     - stats (mean, inv_std ddof=1) from 1024 partials (deterministic tree)
//     - phase0: standardize M in place (float4); K = exp(Mstd - rowmax) kept
//       ENTIRELY IN REGISTERS (thread owns 16 rows x 8 cols = 16x halfx8)
//     - 20 Sinkhorn iters: u = r/(Kv) block-local; t = K^T u via per-block
//       partials tg[256][4096] -> owner col reduce; maxdev via devArr;
//       2 grid barriers per iter
//     - final: w = 1/(Kv); s = K^T w; P_ij = K_ij*w_i/s_j; loss = ||P-I||_F
//     Grid barrier evolution: cg::grid.sync ~4.4us (r1) -> 2-level RMW tree
//     ~2.2us (r2/r3) -> FLAT FLAGS (r4): arrival = 1 parallel release-store
//     per block (no RMW serialization at all); detect = wave0 polls all 256
//     flags with 4 agent-scope loads/lane (one L3 round/poll), __all(min>=gen).

#define NN 4096
#define DIM 1024
#define OT_ITERS 20
#define OT_EPS_F 1e-6f
#define RC (1.0f/4096.0f)
#define RPB 16   // K rows per block
#define SBT 512  // sinkhorn block threads (8 cols each)

typedef __bf16 bf16_t;
typedef _Float16 half_t;
typedef __bf16 bf16x8 __attribute__((ext_vector_type(8)));
typedef _Float16 halfx8 __attribute__((ext_vector_type(8)));
typedef float floatx4 __attribute__((ext_vector_type(4)));

typedef __attribute__((address_space(1))) void gv_t;
typedef __attribute__((address_space(3))) void lv_t;

// async global->LDS, 16B per lane; lds dst = wave-uniform base, HW adds lane*16
__device__ __forceinline__ void gld_lds16(const void* g, void* lds_uniform) {
  uint32_t loff = (uint32_t)(uintptr_t)lds_uniform;
  loff = (uint32_t)__builtin_amdgcn_readfirstlane((int)loff);
  __builtin_amdgcn_global_load_lds((gv_t*)(uintptr_t)g, (lv_t*)(uintptr_t)loff, 16, 0, 0);
}

// ---- flat-flag grid barrier ------------------------------------------------
// flags[256]: one word per block, contiguous (1 KB). Arrival: release store of
// the generation (orders all of this block's prior global stores; same
// primitive family as r2/r3's proven tree barrier). Detect: wave 0 polls the
// whole array, lane covers 4 flags; exit when min >= g; acquire fence then
// block barrier releases the other waves.
__device__ __forceinline__ void gbar(uint32_t* flags, uint32_t g) {
  __syncthreads();  // all waves' stores issued & drained before flag goes up
  int tid = threadIdx.x;
  if (tid == 0)
    __hip_atomic_store(&flags[blockIdx.x], g, __ATOMIC_RELEASE, __HIP_MEMORY_SCOPE_AGENT);
  if (tid < 64) {
    const uint32_t* f = flags + (tid << 2);
    for (;;) {
      uint32_t a = __hip_atomic_load(f + 0, __ATOMIC_RELAXED, __HIP_MEMORY_SCOPE_AGENT);
      uint32_t b = __hip_atomic_load(f + 1, __ATOMIC_RELAXED, __HIP_MEMORY_SCOPE_AGENT);
      uint32_t c = __hip_atomic_load(f + 2, __ATOMIC_RELAXED, __HIP_MEMORY_SCOPE_AGENT);
      uint32_t d = __hip_atomic_load(f + 3, __ATOMIC_RELAXED, __HIP_MEMORY_SCOPE_AGENT);
      uint32_t mn = min(min(a, b), min(c, d));
      if (__all(mn >= g)) break;
      __builtin_amdgcn_s_sleep(1);
    }
    __builtin_amdgcn_fence(__ATOMIC_ACQUIRE, "agent");
  }
  __syncthreads();
}

// ---------------- fused row normalize (ft and fs) + ws init ----------------
__global__ __launch_bounds__(256) void norm_rows2(const float* __restrict__ ft,
                                                  const float* __restrict__ fs,
                                                  bf16_t* __restrict__ A,
                                                  bf16_t* __restrict__ B,
                                                  float* __restrict__ scal,
                                                  uint32_t* __restrict__ flags) {
  int gb = blockIdx.x;  // 0..2047
  const float* X = (gb < 1024) ? ft : fs;
  bf16_t* Y = (gb < 1024) ? A : B;
  int bb = gb & 1023;
  int tid = threadIdx.x;
  int wave = tid >> 6, lane = tid & 63;
  int row = bb * 4 + wave;
  const float* xr = X + (size_t)row * DIM;
  float xv[16];
  float ss = 0.f;
#pragma unroll
  for (int k = 0; k < 16; k++) { xv[k] = xr[lane + 64 * k]; ss += xv[k] * xv[k]; }
#pragma unroll
  for (int off = 1; off < 64; off <<= 1) ss += __shfl_xor(ss, off, 64);
  float inv = rsqrtf(ss);  // norm ~ 32 >> 1e-12 floor, floor never binds
  bf16_t* yr = Y + (size_t)row * DIM;
#pragma unroll
  for (int k = 0; k < 16; k++) yr[lane + 64 * k] = (bf16_t)(xv[k] * inv);
  if (gb == 0) {
    flags[tid] = 0u;                       // 256 barrier flags (replay-safe reset)
    if (tid < 8) ((uint32_t*)scal)[tid] = 0u;  // [4]=lossAcc
  }
}

// ---------------- GEMM: C = A @ B^T (both row-major, K-contiguous) ----------------
__global__ __launch_bounds__(256) void gemm_bt(const bf16_t* __restrict__ A,
                                               const bf16_t* __restrict__ B,
                                               float* __restrict__ C,
                                               float* __restrict__ sumArr,
                                               float* __restrict__ sqArr,
                                               float* __restrict__ rmPart) {
  __shared__ __align__(16) bf16_t As[128 * 32];
  __shared__ __align__(16) bf16_t Bs[128 * 32];
  __shared__ float sred[8];
  int tid = threadIdx.x;
  int wave = tid >> 6, lane = tid & 63;
  int quad = lane >> 4, l16 = lane & 15;
  int bm = blockIdx.y, bn = blockIdx.x;
  int waveM = wave >> 1, waveN = wave & 1;  // 2x2 waves, each 64x64
  floatx4 acc[4][4] = {};

  for (int k0 = 0; k0 < DIM; k0 += 32) {
#pragma unroll
    for (int t = 0; t < 2; t++) {
      int cbase = t * 256 + wave * 64;  // wave-uniform chunk base
      int c = cbase + lane;             // chunk: 16B = 8 bf16
      int row = c >> 2, kc = c & 3;     // tile row, k-subchunk
      gld_lds16(A + (size_t)(bm * 128 + row) * DIM + (k0 + kc * 8), (char*)As + (size_t)cbase * 16);
      gld_lds16(B + (size_t)(bn * 128 + row) * DIM + (k0 + kc * 8), (char*)Bs + (size_t)cbase * 16);
    }
    __syncthreads();  // drains vmcnt before barrier
    bf16x8 af[4], bfr[4];
#pragma unroll
    for (int mt = 0; mt < 4; mt++)
      af[mt] = *(const bf16x8*)(As + (waveM * 64 + mt * 16 + l16) * 32 + quad * 8);
#pragma unroll
    for (int nt = 0; nt < 4; nt++)
      bfr[nt] = *(const bf16x8*)(Bs + (waveN * 64 + nt * 16 + l16) * 32 + quad * 8);
#pragma unroll
    for (int mt = 0; mt < 4; mt++)
#pragma unroll
      for (int nt = 0; nt < 4; nt++)
        acc[mt][nt] = __builtin_amdgcn_mfma_f32_16x16x32_bf16(af[mt], bfr[nt], acc[mt][nt], 0, 0, 0);
    __syncthreads();
  }

  // epilogue: write C (fp32); per-block sum/sq partials; per-block row maxes.
  // C/D layout (m89-verified): col = lane&15, row = quad*4 + reg
  float lsum = 0.f, lsq = 0.f;
#pragma unroll
  for (int mt = 0; mt < 4; mt++) {
#pragma unroll
    for (int r = 0; r < 4; r++) {
      int gi = bm * 128 + waveM * 64 + mt * 16 + quad * 4 + r;
      float rmax = -3.4e38f;
#pragma unroll
      for (int nt = 0; nt < 4; nt++) {
        float vv = acc[mt][nt][r];
        int gj = bn * 128 + waveN * 64 + nt * 16 + l16;
        C[(size_t)gi * NN + gj] = vv;
        lsum += vv;
        lsq += vv * vv;
        rmax = fmaxf(rmax, vv);
      }
#pragma unroll
      for (int off = 1; off < 16; off <<= 1) rmax = fmaxf(rmax, __shfl_xor(rmax, off, 64));
      // each gi is produced by 2 waves (waveN=0/1, different 64-col halves):
      // store per-waveN partial, combine at read time in sinkhorn.
      if (l16 == 0) rmPart[(size_t)(bn * 2 + waveN) * NN + gi] = rmax;
    }
  }
#pragma unroll
  for (int off = 1; off < 64; off <<= 1) {
    lsum += __shfl_xor(lsum, off, 64);
    lsq += __shfl_xor(lsq, off, 64);
  }
  if (lane == 0) { sred[wave] = lsum; sred[4 + wave] = lsq; }
  __syncthreads();
  if (tid == 0) {
    int bid = bm * 32 + bn;
    sumArr[bid] = sred[0] + sred[1] + sred[2] + sred[3];
    sqArr[bid] = sred[4] + sred[5] + sred[6] + sred[7];
  }
}

// ---------------- fused persistent Sinkhorn ----------------
// PLAIN launch: 256 blocks x 512 threads; grid == #CUs -> all co-resident.
// Block b owns K rows [16b,16b+16); thread owns cols [8*tid, 8*tid+8).
__global__ __launch_bounds__(SBT, 1) void sinkhorn_full(
    float* __restrict__ M,            // in: M_raw (GEMM out), out: standardized M
    float* __restrict__ P,            // P output (out+1, NOT 16B aligned -> scalar stores)
    float* __restrict__ scal,         // [4]=lossAcc
    const float* __restrict__ sumArr, // [1024] per-gemm-block sums
    const float* __restrict__ sqArr,  // [1024] per-gemm-block sumsq
    const float* __restrict__ rmPart, // [64][4096] per-(bn,waveN) row maxes
    float* __restrict__ t,            // [4096] colsum K^T u
    float* __restrict__ s,            // [4096] final colsum
    float* __restrict__ tg,           // [256][4096] per-block partials
    float* __restrict__ devArr,       // [256] per-block maxdev
    uint32_t* __restrict__ flags,     // [256] flat barrier flags
    float* __restrict__ out) {        // out[0] = loss
  __shared__ float red[8 * RPB];   // 8 waves x 16 row-partials
  __shared__ float u_lds[RPB];
  __shared__ float scratch[SBT];
  __shared__ float rowmax_l[RPB];
  __shared__ double dred[16];
  __shared__ float stat_l[2];

  const int b = blockIdx.x;
  const int tid = threadIdx.x;
  const int wave = tid >> 6, lane = tid & 63;
  const int g0 = b * RPB;
  const int c0 = tid * 8;  // this thread's 8 columns
  uint32_t bg = 0;         // barrier generation (identical sequence in every block)

  // ---- stats: deterministic tree over 1024 per-block partials (double) ----
  {
    double ds = (double)sumArr[tid] + (double)sumArr[tid + 512];
    double dq = (double)sqArr[tid] + (double)sqArr[tid + 512];
#pragma unroll
    for (int off = 1; off < 64; off <<= 1) {
      ds += __shfl_xor(ds, off, 64);
      dq += __shfl_xor(dq, off, 64);
    }
    if (lane == 0) { dred[wave] = ds; dred[8 + wave] = dq; }
  }
  // ---- per-strip row maxes from rmPart: 16 rows x 64 partials ----
  {
    int row = tid >> 5, half = tid & 31;          // 16 x 32
    float rm = fmaxf(rmPart[(size_t)(half * 2) * NN + g0 + row],
                     rmPart[(size_t)(half * 2 + 1) * NN + g0 + row]);
#pragma unroll
    for (int off = 1; off < 32; off <<= 1) rm = fmaxf(rm, __shfl_xor(rm, off, 64));
    if (half == 0) rowmax_l[row] = rm;
  }
  __syncthreads();
  if (tid == 0) {
    double sum = 0.0, sumsq = 0.0;
#pragma unroll
    for (int w = 0; w < 8; w++) { sum += dred[w]; sumsq += dred[8 + w]; }
    double Nd = (double)NN * (double)NN;
    double meand = sum / Nd;
    double var = (sumsq - sum * sum / Nd) / (Nd - 1.0);  // ddof=1
    stat_l[0] = (float)meand;
    stat_l[1] = (float)(1.0 / sqrt(var));
  }
  __syncthreads();
  const float mean = stat_l[0], istd = stat_l[1];

  // ---- phase 0: standardize M strip in place (float4), K strip in registers ----
  halfx8 kreg[RPB];
#pragma unroll
  for (int i = 0; i < RPB; i++) {
    float rmax = rowmax_l[i];
    float* mrow = M + (size_t)(g0 + i) * NN + c0;
    float4 a = *(const float4*)mrow;
    float4 bb = *(const float4*)(mrow + 4);
    float4 sa, sb;
    sa.x = (a.x - mean) * istd;  sa.y = (a.y - mean) * istd;
    sa.z = (a.z - mean) * istd;  sa.w = (a.w - mean) * istd;
    sb.x = (bb.x - mean) * istd; sb.y = (bb.y - mean) * istd;
    sb.z = (bb.z - mean) * istd; sb.w = (bb.w - mean) * istd;
    *(float4*)mrow = sa;
    *(float4*)(mrow + 4) = sb;
    halfx8 kp;
    kp[0] = (half_t)__expf((a.x - rmax) * istd);
    kp[1] = (half_t)__expf((a.y - rmax) * istd);
    kp[2] = (half_t)__expf((a.z - rmax) * istd);
    kp[3] = (half_t)__expf((a.w - rmax) * istd);
    kp[4] = (half_t)__expf((bb.x - rmax) * istd);
    kp[5] = (half_t)__expf((bb.y - rmax) * istd);
    kp[6] = (half_t)__expf((bb.z - rmax) * istd);
    kp[7] = (half_t)__expf((bb.w - rmax) * istd);
    kreg[i] = kp;
  }

  float vr[8];  // v for this thread's 8 columns (register-resident)
#pragma unroll
  for (int q = 0; q < 8; q++) vr[q] = 1.0f;

  // u_i = scale / sum_j K_ij v_j for block rows; then tg[b][:] = partial K^T u
  auto matvec_phase = [&](float scale) {
    float part[RPB];
#pragma unroll
    for (int i = 0; i < RPB; i++) {
      float p = 0.f;
#pragma unroll
      for (int q = 0; q < 8; q++) p += (float)kreg[i][q] * vr[q];
      part[i] = p;
    }
#pragma unroll
    for (int off = 1; off < 64; off <<= 1)
#pragma unroll
      for (int i = 0; i < RPB; i++) part[i] += __shfl_xor(part[i], off, 64);
    if (lane == 0) {
#pragma unroll
      for (int i = 0; i < RPB; i++) red[wave * RPB + i] = part[i];
    }
    __syncthreads();
    if (tid < RPB) {
      float dsum = 0.f;
#pragma unroll
      for (int w = 0; w < 8; w++) dsum += red[w * RPB + tid];
      u_lds[tid] = scale / dsum;
    }
    __syncthreads();
    float ta[8];
#pragma unroll
    for (int q = 0; q < 8; q++) ta[q] = 0.f;
#pragma unroll
    for (int i = 0; i < RPB; i++) {
      float ui = u_lds[i];
#pragma unroll
      for (int q = 0; q < 8; q++) ta[q] += (float)kreg[i][q] * ui;
    }
    float* tgb = tg + (size_t)b * NN;
#pragma unroll
    for (int q = 0; q < 8; q++) tgb[c0 + q] = ta[q];
  };

  // deterministic fixed-order reduce of tg over 256 blocks for this block's
  // 16 owned columns; result valid for tid < 16
  auto colreduce = [&]() -> float {
    int jl = tid & 15, seg = tid >> 4;  // seg in [0,32), 8 partials each
    int j = g0 + jl;
    float acc = 0.f;
#pragma unroll
    for (int m = 0; m < 8; m++) acc += tg[(size_t)(seg * 8 + m) * NN + j];
    scratch[tid] = acc;
    __syncthreads();
    float tn = 0.f;
    if (tid < RPB) {
#pragma unroll
      for (int k = 0; k < 32; k++) tn += scratch[tid + RPB * k];
    }
    return tn;
  };

  // ---- Sinkhorn loop: u = r/(Kv); t = K^T u; maxdev; v = c/t ----
  bool frozen = false;
  for (int it = 0; it < OT_ITERS; it++) {
    if (it > 0) {
      float4 t0 = *(const float4*)(t + c0);
      float4 t1 = *(const float4*)(t + c0 + 4);
      vr[0] = RC / t0.x; vr[1] = RC / t0.y; vr[2] = RC / t0.z; vr[3] = RC / t0.w;
      vr[4] = RC / t1.x; vr[5] = RC / t1.y; vr[6] = RC / t1.z; vr[7] = RC / t1.w;
    }
    matvec_phase(RC);
    gbar(flags, ++bg);
    float tn = colreduce();
    if (tid < RPB) {
      int j = g0 + tid;
      float vj = (it == 0) ? 1.0f : (RC / t[j]);  // v used THIS iter
      float dev = fabsf(vj * tn - RC);            // beta_j - c
      t[j] = tn;
#pragma unroll
      for (int off = 1; off < RPB; off <<= 1) dev = fmaxf(dev, __shfl_xor(dev, off, 64));
      if (tid == 0) devArr[b] = dev;  // per-block store: no contended atomics
    }
    gbar(flags, ++bg);
    // block-local max over 256 per-block devs (max is exact -> deterministic)
    float x = (tid < 256) ? devArr[tid] : 0.f;
#pragma unroll
    for (int off = 1; off < 64; off <<= 1) x = fmaxf(x, __shfl_xor(x, off, 64));
    if (lane == 0 && wave < 4) scratch[300 + wave] = x;
    __syncthreads();
    float md = fmaxf(fmaxf(scratch[300], scratch[301]), fmaxf(scratch[302], scratch[303]));
    if (md <= OT_EPS_F) { frozen = true; break; }  // uniform across blocks
  }
  if (!frozen) {
#pragma unroll
    for (int q = 0; q < 8; q++) vr[q] = RC / t[c0 + q];  // commit final col-normalize v
  }

  // ---- final: w = 1/(Kv); s = K^T w; P_ij = K_ij * w_i / s_j (v cancels) ----
  matvec_phase(1.0f);  // u_lds now holds w_i
  gbar(flags, ++bg);
  float tn = colreduce();
  if (tid < RPB) s[g0 + tid] = tn;
  gbar(flags, ++bg);

  float4 s0 = *(const float4*)(s + c0);
  float4 s1 = *(const float4*)(s + c0 + 4);
  float isv[8] = {1.0f / s0.x, 1.0f / s0.y, 1.0f / s0.z, 1.0f / s0.w,
                  1.0f / s1.x, 1.0f / s1.y, 1.0f / s1.z, 1.0f / s1.w};
  float ls = 0.f;
#pragma unroll
  for (int i = 0; i < RPB; i++) {
    int gi = g0 + i;
    float wi = u_lds[i];
    float* prow = P + (size_t)gi * NN;  // unaligned base (out+1): scalar stores
#pragma unroll
    for (int q = 0; q < 8; q++) {
      float p = (float)kreg[i][q] * wi * isv[q];
      prow[c0 + q] = p;
      float d = p - ((gi == c0 + q) ? 1.0f : 0.0f);
      ls += d * d;
    }
  }
#pragma unroll
  for (int off = 1; off < 64; off <<= 1) ls += __shfl_xor(ls, off, 64);
  __syncthreads();
  if (lane == 0) red[wave] = ls;
  __syncthreads();
  if (tid == 0) {
    float tot = 0.f;
#pragma unroll
    for (int w = 0; w < 8; w++) tot += red[w];
    atomicAdd(&scal[4], tot);
  }
  gbar(flags, ++bg);
  if (b == 0 && tid == 0) out[0] = sqrtf(scal[4]);
}

// ---------------- launch ----------------
extern "C" void kernel_launch(void* const* d_in, const int* in_sizes, int n_in, void* d_out,
                              int out_size, void* d_ws, size_t ws_size, hipStream_t stream) {
  const float* ft = (const float*)d_in[0];
  const float* fs = (const float*)d_in[1];
  float* out = (float*)d_out;

  char* ws = (char*)d_ws;
  bf16_t* A = (bf16_t*)ws;                  //  8 MiB
  bf16_t* B = (bf16_t*)(ws + (8u << 20));   //  8 MiB
  float* tg = (float*)(ws + (16u << 20));   //  4 MiB: per-block col partials
  float* fbase = (float*)(ws + (24u << 20));
  float* t = fbase;                              // 4096
  float* s = fbase + 4096;                       // 4096
  float* devArr = fbase + 8192;                  // 256
  float* scal = fbase + 8448;                    // 8 ([4]=lossAcc)
  uint32_t* flags = (uint32_t*)(fbase + 8704);   // 256 flat barrier flags
  float* sumArr = fbase + 10240;                 // 1024
  float* sqArr = fbase + 11264;                  // 1024
  float* rmPart = fbase + 16384;                 // 64*4096 (per bn x waveN row maxes)

  float* P_out = out + 1;
  float* M_out = out + 1 + (size_t)NN * NN;  // scratch for M_raw, then standardized M

  norm_rows2<<<2048, 256, 0, stream>>>(ft, fs, A, B, scal, flags);
  gemm_bt<<<dim3(32, 32), 256, 0, stream>>>(A, B, M_out, sumArr, sqArr, rmPart);

  sinkhorn_full<<<256, SBT, 0, stream>>>(M_out, P_out, scal, sumArr, sqArr, rmPart, t, s, tg,
                                         devArr, flags, out);
}